// Round 7
// baseline (187.493 us; speedup 1.0000x reference)
//
#include <hip/hip_runtime.h>

#define NCH 80
#define HW 16384

typedef unsigned short u16;
typedef unsigned int u32;
typedef short s16x8 __attribute__((ext_vector_type(8)));
typedef float f32x4 __attribute__((ext_vector_type(4)));

__device__ __forceinline__ float b2f_lo(u32 pk){ union{u32 u; float f;} c; c.u = pk<<16; return c.f; }
__device__ __forceinline__ float b2f_hi(u32 pk){ union{u32 u; float f;} c; c.u = pk & 0xffff0000u; return c.f; }
__device__ __forceinline__ u16 f2b_hw(float f){
    union{ __bf16 h; u16 s; } c; c.h = (__bf16)f; return c.s;
}
__device__ __forceinline__ u32 pk2(float a, float b){
    return (u32)f2b_hw(a) | ((u32)f2b_hw(b)<<16);
}
#define NEG_INF (-__builtin_inff())

union U4S8 { uint4 u; s16x8 v; };

// LDS px-swizzle (word granularity, involution, multiples of 4 words = 16B chunks)
__device__ __forceinline__ int swz_px(int cin, int px){
    int q = cin >> 3;
    return px ^ ((q & 3) << 2) ^ ((q & 1) << 4);
}

// async global->LDS, 16B per lane, LDS dest = uniform base + lane*16
__device__ __forceinline__ void gload_lds16(const void* g, void* l){
    __builtin_amdgcn_global_load_lds(
        (const __attribute__((address_space(1))) void*)g,
        (__attribute__((address_space(3))) void*)l,
        16, 0, 0);
}

// ---------------------------------------------------------------- P0: weight pack -> bf16
__global__ __launch_bounds__(256) void k_wcvt(
    const float* __restrict__ qw, const float* __restrict__ qb,
    const float* __restrict__ kw, const float* __restrict__ kb,
    const float* __restrict__ vw, const float* __restrict__ vb,
    u16* __restrict__ wbf, float* __restrict__ bias80)
{
    int i = blockIdx.x*256 + threadIdx.x;     // 0..10239
    int ch = i >> 7, cin = i & 127;
    float v;
    if (ch < 8)       v = (cin < 64) ? qw[ch*64 + cin] : 0.f;
    else if (ch < 16) v = (cin >= 64) ? kw[(ch-8)*64 + (cin-64)] : 0.f;
    else              v = vw[(ch-16)*128 + cin];
    wbf[i] = f2b_hw(v);
    if (i < 80){
        bias80[i] = (i<8) ? qb[i] : (i<16) ? kb[i-8] : vb[i-16];
    }
}

// ---------------------------------------------------------------- P1: qkv via MFMA, global_load_lds staging
// Block = 256 thr (4 waves), 64 pixels. f32 [cin][px^swz] tile (32 KB) staged
// via direct-to-LDS loads; convert to bf16 at fragment build; fused xy emit.
__global__ __launch_bounds__(256) void k_qkv_mfma(
    const float* __restrict__ x, const float* __restrict__ y,
    const u16* __restrict__ wbf, const float* __restrict__ bias80,
    u16* __restrict__ qkv, u16* __restrict__ xy)
{
    __shared__ float xs_lds[128*64];   // 32 KB: word = cin*64 + (px ^ swz(cin))

    int t = threadIdx.x;
    int wv = t >> 6, l = t & 63;
    int p0 = blockIdx.x * 64;
    int b = p0 >> 14, rem = p0 & 16383;

    const float* xb = x + (size_t)b*64*HW + rem;
    const float* yb = y + (size_t)b*64*HW + rem;

    // ---- stage 32 segments x 1KB; wave wv owns segments [wv*8, wv*8+8)
    #pragma unroll
    for (int i=0;i<8;i++){
        int s = wv*8 + i;                        // cin quad
        int cin = s*4 + (l>>4);
        int pxg = swz_px(cin, (l&15)*4);         // pre-swizzled global px
        const float* gp = (cin < 64) ? (xb + (size_t)cin*HW + pxg)
                                     : (yb + (size_t)(cin-64)*HW + pxg);
        gload_lds16(gp, (char*)xs_lds + s*1024); // dest uniform base + lane*16
    }
    __syncthreads();

    int lm = l & 15, lq = l >> 4;
    int px = wv*16 + lm;

    // ---- A fragments: k = ks*32 + lq*8 + j  <->  cin (x: 0-63, y: 64-127)
    s16x8 af[4];
    #pragma unroll
    for (int ks=0; ks<4; ks++){
        float fv[8];
        #pragma unroll
        for (int j=0;j<8;j++){
            int cin = ks*32 + lq*8 + j;
            fv[j] = xs_lds[cin*64 + swz_px(cin, px)];
        }
        U4S8 uu;
        uu.u = make_uint4(pk2(fv[0],fv[1]), pk2(fv[2],fv[3]),
                          pk2(fv[4],fv[5]), pk2(fv[6],fv[7]));
        af[ks] = uu.v;
    }

    // ---- MFMA: 1 m-tile (16 px) x 5 n-tiles x K=128
    #pragma unroll
    for (int nt=0;nt<5;nt++){
        int ch = nt*16 + lm;
        const u16* wrow = wbf + ch*128 + lq*8;
        f32x4 acc = (f32x4){0.f,0.f,0.f,0.f};
        #pragma unroll
        for (int ks=0;ks<4;ks++){
            s16x8 bfrag = *(const s16x8*)(wrow + ks*32);
            acc = __builtin_amdgcn_mfma_f32_16x16x32_bf16(af[ks], bfrag, acc, 0,0,0);
        }
        float bs = bias80[ch];
        uint2 st;
        st.x = pk2(acc[0]+bs, acc[1]+bs);
        st.y = pk2(acc[2]+bs, acc[3]+bs);
        *(uint2*)&qkv[(size_t)(b*NCH + ch)*HW + rem + wv*16 + lq*4] = st;
    }

    // ---- fused xy emit: xy = bf16(x+y), natural layout, coalesced u32 stores
    if (xy){
        u32* xyp = (u32*)xy;
        #pragma unroll
        for (int r=0;r<8;r++){
            int oi = t + r*256;          // 0..2047
            int ch = oi >> 5;            // 0..63
            int pxp = oi & 31;           // u32 (pixel-pair) index
            int wx = ch*64 + swz_px(ch, 2*pxp);
            int wyi = (ch+64)*64 + swz_px(ch+64, 2*pxp);
            float2 xv = *(float2*)&xs_lds[wx];
            float2 yv = *(float2*)&xs_lds[wyi];
            xyp[((size_t)(b*64+ch)*HW + rem)/2 + pxp] = pk2(xv.x+yv.x, xv.y+yv.y);
        }
    }
}

// ------------------------------------------------ 128x128 bf16 plane transpose (unchanged)
__global__ __launch_bounds__(256) void k_tr(const u16* __restrict__ src, u16* __restrict__ dst)
{
    __shared__ u16 tile[64][65];
    int blk = blockIdx.x;
    int plane = blk >> 2, tq = blk & 3;
    int r0 = (tq >> 1) * 64, c0 = (tq & 1) * 64;
    const u16* s = src + (size_t)plane * HW;
    u16* d = dst + (size_t)plane * HW;
    int col = threadIdx.x & 63, rr = threadIdx.x >> 6;
    #pragma unroll
    for (int k=0;k<16;k++){
        int r = k*4 + rr;
        tile[r][col] = s[(r0+r)*128 + c0 + col];
    }
    __syncthreads();
    #pragma unroll
    for (int k=0;k<16;k++){
        int r = k*4 + rr;
        d[(c0+r)*128 + r0 + col] = tile[col][r];
    }
}

// ---------------------------------------------------------------- P2: column pass (MFMA PV)
__global__ __launch_bounds__(512, 4) void k_col(
    const u16* __restrict__ qkvT, u16* __restrict__ colT,
    float* __restrict__ mH, float* __restrict__ sH)
{
    __shared__ __align__(16) float q_s[8*128];    // [o][h]
    __shared__ __align__(16) float k_sw[8*128];   // [g][o^((g>>3)&7)]
    __shared__ __align__(16) u16  v_bf[64*128];   // [c][g], word ^ ((c&7)<<2)
    __shared__ __align__(16) u16  p_bf[128*128];  // [h][g], word ^ ((h&7)<<2)

    int t = threadIdx.x;
    int b = blockIdx.x >> 7, w = blockIdx.x & 127;
    const u32* src = (const u32*)(qkvT + (size_t)b*NCH*HW + w*128);
    u32* v32 = (u32*)v_bf;
    u32* p32 = (u32*)p_bf;

    #pragma unroll
    for (int r=0;r<2;r++){
        int idx = t + r*512;
        int ch = idx >> 6, hp = idx & 63;
        u32 pk = src[ch*8192 + hp];
        int g0 = hp*2;
        if (ch < 8){
            *(float2*)&q_s[ch*128 + g0] = make_float2(b2f_lo(pk), b2f_hi(pk));
        } else {
            int o = ch - 8;
            k_sw[g0*8     + (o ^ ((g0>>3)&7))]     = b2f_lo(pk);
            k_sw[(g0+1)*8 + (o ^ (((g0+1)>>3)&7))] = b2f_hi(pk);
        }
    }
    #pragma unroll
    for (int r=0;r<8;r++){
        int idx = t + r*512;
        int c = idx >> 6, gp = idx & 63;
        v32[(c*64 + gp) ^ ((c&7)<<2)] = src[(16+c)*8192 + gp];
    }
    __syncthreads();

    int tr = t >> 4, tc = t & 15;
    int h0 = tr*4, g0 = tc*8;
    float e[4][8];
    #pragma unroll
    for (int i=0;i<4;i++)
        #pragma unroll
        for (int j=0;j<8;j++) e[i][j] = 0.f;

    #pragma unroll
    for (int o=0;o<8;o++){
        float qv[4], kv[8];
        #pragma unroll
        for (int i=0;i<4;i++) qv[i] = q_s[o*128 + h0 + i];
        int kb = o ^ (tc & 7);
        #pragma unroll
        for (int j=0;j<8;j++) kv[j] = k_sw[(g0+j)*8 + kb];
        #pragma unroll
        for (int i=0;i<4;i++)
            #pragma unroll
            for (int j=0;j<8;j++) e[i][j] += qv[i]*kv[j];
    }
    #pragma unroll
    for (int i=0;i<4;i++){
        int h = h0 + i;
        if ((h>>3) == tc) e[i][h&7] = NEG_INF;
    }
    #pragma unroll
    for (int i=0;i<4;i++){
        int h = h0 + i;
        float m = e[i][0];
        #pragma unroll
        for (int j=1;j<8;j++) m = fmaxf(m, e[i][j]);
        m = fmaxf(m, __shfl_xor(m,1));
        m = fmaxf(m, __shfl_xor(m,2));
        m = fmaxf(m, __shfl_xor(m,4));
        m = fmaxf(m, __shfl_xor(m,8));
        float s = 0.f;
        #pragma unroll
        for (int j=0;j<8;j++){ float pp = __expf(e[i][j]-m); e[i][j]=pp; s += pp; }
        s += __shfl_xor(s,1);
        s += __shfl_xor(s,2);
        s += __shfl_xor(s,4);
        s += __shfl_xor(s,8);
        if (tc == 0){
            mH[b*HW + h*128 + w] = m;
            sH[b*HW + h*128 + w] = s;
        }
        uint4 pw;
        pw.x = pk2(e[i][0], e[i][1]);
        pw.y = pk2(e[i][2], e[i][3]);
        pw.z = pk2(e[i][4], e[i][5]);
        pw.w = pk2(e[i][6], e[i][7]);
        *(uint4*)&p32[(h*64 + tc*4) ^ ((h&7)<<2)] = pw;
    }
    __syncthreads();

    int wv = t >> 6, l = t & 63;
    int lm = l & 15, lq = l >> 4;
    int mt = wv;
    f32x4 acc[4];
    #pragma unroll
    for (int nt=0; nt<4; nt++) acc[nt] = (f32x4){0.f,0.f,0.f,0.f};

    #pragma unroll
    for (int ks=0; ks<4; ks++){
        int ri = mt*16 + lm;
        s16x8 a = *(const s16x8*)&p32[(ri*64 + ks*16 + lq*4) ^ ((ri&7)<<2)];
        #pragma unroll
        for (int nt=0; nt<4; nt++){
            int c = nt*16 + lm;
            s16x8 bf_ = *(const s16x8*)&v32[(c*64 + ks*16 + lq*4) ^ ((c&7)<<2)];
            acc[nt] = __builtin_amdgcn_mfma_f32_16x16x32_bf16(a, bf_, acc[nt], 0, 0, 0);
        }
    }
    #pragma unroll
    for (int nt=0; nt<4; nt++){
        int c = nt*16 + lm;
        int hh = mt*16 + lq*4;
        uint2 st;
        st.x = pk2(acc[nt][0], acc[nt][1]);
        st.y = pk2(acc[nt][2], acc[nt][3]);
        *(uint2*)&colT[((size_t)(b*64+c)*128 + w)*128 + hh] = st;
    }
}

// ---------------------------------------------------------------- P3: row pass + combine (MFMA PV)
__global__ __launch_bounds__(512, 4) void k_row(
    const u16* __restrict__ qkv, const u16* __restrict__ colpart,
    const float* __restrict__ mH, const float* __restrict__ sH,
    const float* __restrict__ x, const float* __restrict__ y,
    const u16* __restrict__ xy,
    const float* __restrict__ gamma_p, float* __restrict__ out)
{
    __shared__ __align__(16) float q_s[8*128];
    __shared__ __align__(16) float k_sw[8*128];
    __shared__ __align__(16) u16  v_bf[64*128];
    __shared__ __align__(16) u16  p_bf[128*128];
    __shared__ float fc_s[128], fr_s[128];

    int t = threadIdx.x;
    int b = blockIdx.x >> 7, h = blockIdx.x & 127;
    const u32* src = (const u32*)(qkv + (size_t)b*NCH*HW + h*128);
    u32* v32 = (u32*)v_bf;
    u32* p32 = (u32*)p_bf;

    #pragma unroll
    for (int r=0;r<2;r++){
        int idx = t + r*512;
        int ch = idx >> 6, wp = idx & 63;
        u32 pk = src[ch*8192 + wp];
        int u0 = wp*2;
        if (ch < 8){
            *(float2*)&q_s[ch*128 + u0] = make_float2(b2f_lo(pk), b2f_hi(pk));
        } else {
            int o = ch - 8;
            k_sw[u0*8     + (o ^ ((u0>>3)&7))]     = b2f_lo(pk);
            k_sw[(u0+1)*8 + (o ^ (((u0+1)>>3)&7))] = b2f_hi(pk);
        }
    }
    #pragma unroll
    for (int r=0;r<8;r++){
        int idx = t + r*512;
        int c = idx >> 6, up = idx & 63;
        v32[(c*64 + up) ^ ((c&7)<<2)] = src[(16+c)*8192 + up];
    }
    __syncthreads();

    int tr = t >> 4, tc = t & 15;
    int w0 = tr*4, u0 = tc*8;
    float e[4][8];
    #pragma unroll
    for (int i=0;i<4;i++)
        #pragma unroll
        for (int j=0;j<8;j++) e[i][j] = 0.f;

    #pragma unroll
    for (int o=0;o<8;o++){
        float qv[4], kv[8];
        #pragma unroll
        for (int i=0;i<4;i++) qv[i] = q_s[o*128 + w0 + i];
        int kb = o ^ (tc & 7);
        #pragma unroll
        for (int j=0;j<8;j++) kv[j] = k_sw[(u0+j)*8 + kb];
        #pragma unroll
        for (int i=0;i<4;i++)
            #pragma unroll
            for (int j=0;j<8;j++) e[i][j] += qv[i]*kv[j];
    }
    int pixbase = b*HW + h*128;
    #pragma unroll
    for (int i=0;i<4;i++){
        int wp = w0 + i;
        float m = e[i][0];
        #pragma unroll
        for (int j=1;j<8;j++) m = fmaxf(m, e[i][j]);
        m = fmaxf(m, __shfl_xor(m,1));
        m = fmaxf(m, __shfl_xor(m,2));
        m = fmaxf(m, __shfl_xor(m,4));
        m = fmaxf(m, __shfl_xor(m,8));
        float mh = mH[pixbase + wp];
        float sh = sH[pixbase + wp];
        float mg = fmaxf(m, mh);
        float s = 0.f;
        #pragma unroll
        for (int j=0;j<8;j++){ float pp = __expf(e[i][j]-mg); e[i][j]=pp; s += pp; }
        s += __shfl_xor(s,1);
        s += __shfl_xor(s,2);
        s += __shfl_xor(s,4);
        s += __shfl_xor(s,8);
        if (tc == 0){
            float ef = __expf(mh - mg);
            float stot = sh*ef + s;
            fc_s[wp] = ef/stot;
            fr_s[wp] = 1.0f/stot;
        }
        uint4 pw;
        pw.x = pk2(e[i][0], e[i][1]);
        pw.y = pk2(e[i][2], e[i][3]);
        pw.z = pk2(e[i][4], e[i][5]);
        pw.w = pk2(e[i][6], e[i][7]);
        *(uint4*)&p32[(wp*64 + tc*4) ^ ((wp&7)<<2)] = pw;
    }
    __syncthreads();

    int wv = t >> 6, l = t & 63;
    int lm = l & 15, lq = l >> 4;
    int mt = wv;
    f32x4 acc[4];
    #pragma unroll
    for (int nt=0; nt<4; nt++) acc[nt] = (f32x4){0.f,0.f,0.f,0.f};

    #pragma unroll
    for (int ks=0; ks<4; ks++){
        int ri = mt*16 + lm;
        s16x8 a = *(const s16x8*)&p32[(ri*64 + ks*16 + lq*4) ^ ((ri&7)<<2)];
        #pragma unroll
        for (int nt=0; nt<4; nt++){
            int c = nt*16 + lm;
            s16x8 bf_ = *(const s16x8*)&v32[(c*64 + ks*16 + lq*4) ^ ((c&7)<<2)];
            acc[nt] = __builtin_amdgcn_mfma_f32_16x16x32_bf16(a, bf_, acc[nt], 0, 0, 0);
        }
    }
    float gm = gamma_p[0];
    int wq0 = mt*16 + lq*4;
    float fcv[4], frv[4];
    #pragma unroll
    for (int r2=0;r2<4;r2++){ fcv[r2] = fc_s[wq0+r2]; frv[r2] = fr_s[wq0+r2]; }

    #pragma unroll
    for (int nt=0; nt<4; nt++){
        int c = nt*16 + lm;
        size_t off = ((size_t)(b*64+c)*128 + h)*128 + wq0;
        uint2 cpv = *(const uint2*)&colpart[off];
        float cp[4] = {b2f_lo(cpv.x), b2f_hi(cpv.x), b2f_lo(cpv.y), b2f_hi(cpv.y)};
        float xs[4];
        if (xy){
            uint2 xv = *(const uint2*)&xy[off];
            xs[0]=b2f_lo(xv.x); xs[1]=b2f_hi(xv.x); xs[2]=b2f_lo(xv.y); xs[3]=b2f_hi(xv.y);
        } else {
            float4 x4 = *(const float4*)&x[off];
            float4 y4 = *(const float4*)&y[off];
            xs[0]=x4.x+y4.x; xs[1]=x4.y+y4.y; xs[2]=x4.z+y4.z; xs[3]=x4.w+y4.w;
        }
        float4 o4;
        o4.x = gm*(cp[0]*fcv[0] + acc[nt][0]*frv[0]) + xs[0];
        o4.y = gm*(cp[1]*fcv[1] + acc[nt][1]*frv[1]) + xs[1];
        o4.z = gm*(cp[2]*fcv[2] + acc[nt][2]*frv[2]) + xs[2];
        o4.w = gm*(cp[3]*fcv[3] + acc[nt][3]*frv[3]) + xs[3];
        *(float4*)&out[off] = o4;
    }
}

// ----------------------------------------------------------------
extern "C" void kernel_launch(void* const* d_in, const int* in_sizes, int n_in,
                              void* d_out, int out_size, void* d_ws, size_t ws_size,
                              hipStream_t stream)
{
    (void)in_sizes; (void)n_in; (void)out_size;
    const float* x  = (const float*)d_in[0];
    const float* y  = (const float*)d_in[1];
    const float* qw = (const float*)d_in[2];
    const float* qb = (const float*)d_in[3];
    const float* kw = (const float*)d_in[4];
    const float* kb = (const float*)d_in[5];
    const float* vw = (const float*)d_in[6];
    const float* vb = (const float*)d_in[7];
    const float* gm = (const float*)d_in[8];
    float* out = (float*)d_out;

    char* ws = (char*)d_ws;
    u16* qkv     = (u16*)(ws);                    // 41,943,040 B
    u16* qkvT    = (u16*)(ws + 41943040ull);      // 41,943,040 B
    u16* colT    = (u16*)(ws + 83886080ull);      // 33,554,432 B
    u16* colpart = qkvT;                          // alias: qkvT dead after k_col
    float* mH    = (float*)(ws + 117440512ull);   // 1,048,576 B
    float* sH    = (float*)(ws + 118489088ull);   // 1,048,576 B
    u16* wbf     = (u16*)(ws + 119537664ull);     // 20,480 B
    float* bias80= (float*)(ws + 119558144ull);   // 320 B
    u16* xybuf   = nullptr;                       // 33,554,432 B (optional)
    if (ws_size >= 119603200ull + 33554432ull)
        xybuf = (u16*)(ws + 119603200ull);

    k_wcvt<<<40, 256, 0, stream>>>(qw, qb, kw, kb, vw, vb, wbf, bias80);
    k_qkv_mfma<<<4096, 256, 0, stream>>>(x, y, wbf, bias80, qkv, xybuf);
    k_tr <<<5120, 256, 0, stream>>>(qkv, qkvT);          // 1280 planes
    k_col<<<2048, 512, 0, stream>>>(qkvT, colT, mH, sH);
    k_tr <<<4096, 256, 0, stream>>>(colT, colpart);      // 1024 planes
    k_row<<<2048, 512, 0, stream>>>(qkv, colpart, mH, sH, x, y, xybuf, gm, out);
}

// Round 8
// 170.050 us; speedup vs baseline: 1.1026x; 1.1026x over previous
//
#include <hip/hip_runtime.h>

#define NCH 80
#define HW 16384

typedef unsigned short u16;
typedef unsigned int u32;
typedef short s16x8 __attribute__((ext_vector_type(8)));
typedef float f32x4 __attribute__((ext_vector_type(4)));

__device__ __forceinline__ float b2f_lo(u32 pk){ union{u32 u; float f;} c; c.u = pk<<16; return c.f; }
__device__ __forceinline__ float b2f_hi(u32 pk){ union{u32 u; float f;} c; c.u = pk & 0xffff0000u; return c.f; }
__device__ __forceinline__ u16 f2b_hw(float f){
    union{ __bf16 h; u16 s; } c; c.h = (__bf16)f; return c.s;
}
__device__ __forceinline__ u32 pk2(float a, float b){
    return (u32)f2b_hw(a) | ((u32)f2b_hw(b)<<16);
}
#define NEG_INF (-__builtin_inff())

union U4S8 { uint4 u; s16x8 v; };

// LDS px-swizzle (word granularity, involution, multiples of 4 words = 16B chunks)
__device__ __forceinline__ int swz_px(int cin, int px){
    int q = cin >> 3;
    return px ^ ((q & 3) << 2) ^ ((q & 1) << 4);
}

// async global->LDS, 16B per lane, LDS dest = uniform base + lane*16
__device__ __forceinline__ void gload_lds16(const void* g, void* l){
    __builtin_amdgcn_global_load_lds(
        (const __attribute__((address_space(1))) void*)g,
        (__attribute__((address_space(3))) void*)l,
        16, 0, 0);
}

// ---------------------------------------------------------------- P0: weight pack -> bf16
__global__ __launch_bounds__(256) void k_wcvt(
    const float* __restrict__ qw, const float* __restrict__ qb,
    const float* __restrict__ kw, const float* __restrict__ kb,
    const float* __restrict__ vw, const float* __restrict__ vb,
    u16* __restrict__ wbf, float* __restrict__ bias80)
{
    int i = blockIdx.x*256 + threadIdx.x;     // 0..10239
    int ch = i >> 7, cin = i & 127;
    float v;
    if (ch < 8)       v = (cin < 64) ? qw[ch*64 + cin] : 0.f;
    else if (ch < 16) v = (cin >= 64) ? kw[(ch-8)*64 + (cin-64)] : 0.f;
    else              v = vw[(ch-16)*128 + cin];
    wbf[i] = f2b_hw(v);
    if (i < 80){
        bias80[i] = (i<8) ? qb[i] : (i<16) ? kb[i-8] : vb[i-16];
    }
}

// ---------------------------------------------------------------- P1: qkv via MFMA
// Block = 256 thr (4 waves), 128 px. 64KB f32 LDS [cin][px^f(cin)] staged via
// global_load_lds (16 x 1KB per wave, fully async). 2 blocks/CU overlap.
__global__ __launch_bounds__(256) void k_qkv_mfma(
    const float* __restrict__ x, const float* __restrict__ y,
    const u16* __restrict__ wbf, const float* __restrict__ bias80,
    u16* __restrict__ qkv, u16* __restrict__ xy)
{
    __shared__ float xs_lds[128*128];   // 64 KB: word = cin*128 + (px ^ f(cin))

    int t = threadIdx.x;
    int wv = t >> 6, l = t & 63;
    int p0 = blockIdx.x * 128;
    int b = p0 >> 14, rem = p0 & 16383;

    const float* xb = x + (size_t)b*64*HW + rem;
    const float* yb = y + (size_t)b*64*HW + rem;

    // ---- stage 64 segments x 1KB (2 cin-rows each); wave wv owns 16
    #pragma unroll
    for (int i=0;i<16;i++){
        int s = wv*16 + i;                       // cin pair index 0..63
        int cin = s*2 + (l>>5);
        int pxg = swz_px(cin, (l&31)*4);         // pre-swizzled global px
        const float* gp = (cin < 64) ? (xb + (size_t)cin*HW + pxg)
                                     : (yb + (size_t)(cin-64)*HW + pxg);
        gload_lds16(gp, (char*)xs_lds + s*1024);
    }
    __syncthreads();

    int lm = l & 15, lq = l >> 4;

    // ---- A fragments: px = (wv*2+m2)*16+lm, k = ks*32 + lq*8 + j
    s16x8 af[2][4];
    #pragma unroll
    for (int m2=0;m2<2;m2++){
        int px = (wv*2 + m2)*16 + lm;
        #pragma unroll
        for (int ks=0; ks<4; ks++){
            int cin0 = ks*32 + lq*8;
            int pxs = swz_px(cin0, px);          // same f for all 8 j (j<8, cin>>3 fixed)
            float fv[8];
            #pragma unroll
            for (int j=0;j<8;j++) fv[j] = xs_lds[(cin0+j)*128 + pxs];
            U4S8 uu;
            uu.u = make_uint4(pk2(fv[0],fv[1]), pk2(fv[2],fv[3]),
                              pk2(fv[4],fv[5]), pk2(fv[6],fv[7]));
            af[m2][ks] = uu.v;
        }
    }

    // ---- MFMA: 2 m-tiles x 5 n-tiles x K=128
    #pragma unroll
    for (int nt=0;nt<5;nt++){
        int ch = nt*16 + lm;
        const u16* wrow = wbf + ch*128 + lq*8;
        s16x8 b0 = *(const s16x8*)(wrow);
        s16x8 b1 = *(const s16x8*)(wrow + 32);
        s16x8 b2 = *(const s16x8*)(wrow + 64);
        s16x8 b3 = *(const s16x8*)(wrow + 96);
        f32x4 acc0 = (f32x4){0.f,0.f,0.f,0.f};
        f32x4 acc1 = (f32x4){0.f,0.f,0.f,0.f};
        acc0 = __builtin_amdgcn_mfma_f32_16x16x32_bf16(af[0][0], b0, acc0, 0,0,0);
        acc1 = __builtin_amdgcn_mfma_f32_16x16x32_bf16(af[1][0], b0, acc1, 0,0,0);
        acc0 = __builtin_amdgcn_mfma_f32_16x16x32_bf16(af[0][1], b1, acc0, 0,0,0);
        acc1 = __builtin_amdgcn_mfma_f32_16x16x32_bf16(af[1][1], b1, acc1, 0,0,0);
        acc0 = __builtin_amdgcn_mfma_f32_16x16x32_bf16(af[0][2], b2, acc0, 0,0,0);
        acc1 = __builtin_amdgcn_mfma_f32_16x16x32_bf16(af[1][2], b2, acc1, 0,0,0);
        acc0 = __builtin_amdgcn_mfma_f32_16x16x32_bf16(af[0][3], b3, acc0, 0,0,0);
        acc1 = __builtin_amdgcn_mfma_f32_16x16x32_bf16(af[1][3], b3, acc1, 0,0,0);
        float bs = bias80[ch];
        size_t chbase = (size_t)(b*NCH + ch)*HW + rem;
        uint2 st0, st1;
        st0.x = pk2(acc0[0]+bs, acc0[1]+bs);
        st0.y = pk2(acc0[2]+bs, acc0[3]+bs);
        st1.x = pk2(acc1[0]+bs, acc1[1]+bs);
        st1.y = pk2(acc1[2]+bs, acc1[3]+bs);
        *(uint2*)&qkv[chbase + (wv*2+0)*16 + lq*4] = st0;
        *(uint2*)&qkv[chbase + (wv*2+1)*16 + lq*4] = st1;
    }

    // ---- fused xy emit: xy = bf16(x)+bf16(y) from LDS, coalesced u32 stores
    if (xy){
        u32* xyp = (u32*)xy;
        #pragma unroll
        for (int r=0;r<16;r++){
            int oi = t + r*256;          // 0..4095
            int ch = oi >> 6;            // 0..63
            int pp = oi & 63;            // u32 pixel-pair within 128 px
            int wx  = ch*128      + (2*pp ^ (swz_px(ch,0)));
            int wyi = (ch+64)*128 + (2*pp ^ (swz_px(ch+64,0)));
            float2 xv = *(float2*)&xs_lds[wx];
            float2 yv = *(float2*)&xs_lds[wyi];
            xyp[((size_t)(b*64+ch)*HW + rem)/2 + pp] = pk2(xv.x+yv.x, xv.y+yv.y);
        }
    }
}

// ------------------------------------------------ 128x128 bf16 plane transpose (unchanged)
__global__ __launch_bounds__(256) void k_tr(const u16* __restrict__ src, u16* __restrict__ dst)
{
    __shared__ u16 tile[64][65];
    int blk = blockIdx.x;
    int plane = blk >> 2, tq = blk & 3;
    int r0 = (tq >> 1) * 64, c0 = (tq & 1) * 64;
    const u16* s = src + (size_t)plane * HW;
    u16* d = dst + (size_t)plane * HW;
    int col = threadIdx.x & 63, rr = threadIdx.x >> 6;
    #pragma unroll
    for (int k=0;k<16;k++){
        int r = k*4 + rr;
        tile[r][col] = s[(r0+r)*128 + c0 + col];
    }
    __syncthreads();
    #pragma unroll
    for (int k=0;k<16;k++){
        int r = k*4 + rr;
        d[(c0+r)*128 + r0 + col] = tile[col][r];
    }
}

// ---------------------------------------------------------------- P2: column pass (MFMA PV)
__global__ __launch_bounds__(512, 4) void k_col(
    const u16* __restrict__ qkvT, u16* __restrict__ colT,
    float* __restrict__ mH, float* __restrict__ sH)
{
    __shared__ __align__(16) float q_s[8*128];    // [o][h]
    __shared__ __align__(16) float k_sw[8*128];   // [g][o^((g>>3)&7)]
    __shared__ __align__(16) u16  v_bf[64*128];   // [c][g], word ^ ((c&7)<<2)
    __shared__ __align__(16) u16  p_bf[128*128];  // [h][g], word ^ ((h&7)<<2)

    int t = threadIdx.x;
    int b = blockIdx.x >> 7, w = blockIdx.x & 127;
    const u32* src = (const u32*)(qkvT + (size_t)b*NCH*HW + w*128);
    u32* v32 = (u32*)v_bf;
    u32* p32 = (u32*)p_bf;

    #pragma unroll
    for (int r=0;r<2;r++){
        int idx = t + r*512;
        int ch = idx >> 6, hp = idx & 63;
        u32 pk = src[ch*8192 + hp];
        int g0 = hp*2;
        if (ch < 8){
            *(float2*)&q_s[ch*128 + g0] = make_float2(b2f_lo(pk), b2f_hi(pk));
        } else {
            int o = ch - 8;
            k_sw[g0*8     + (o ^ ((g0>>3)&7))]     = b2f_lo(pk);
            k_sw[(g0+1)*8 + (o ^ (((g0+1)>>3)&7))] = b2f_hi(pk);
        }
    }
    #pragma unroll
    for (int r=0;r<8;r++){
        int idx = t + r*512;
        int c = idx >> 6, gp = idx & 63;
        v32[(c*64 + gp) ^ ((c&7)<<2)] = src[(16+c)*8192 + gp];
    }
    __syncthreads();

    int tr = t >> 4, tc = t & 15;
    int h0 = tr*4, g0 = tc*8;
    float e[4][8];
    #pragma unroll
    for (int i=0;i<4;i++)
        #pragma unroll
        for (int j=0;j<8;j++) e[i][j] = 0.f;

    #pragma unroll
    for (int o=0;o<8;o++){
        float qv[4], kv[8];
        #pragma unroll
        for (int i=0;i<4;i++) qv[i] = q_s[o*128 + h0 + i];
        int kb = o ^ (tc & 7);
        #pragma unroll
        for (int j=0;j<8;j++) kv[j] = k_sw[(g0+j)*8 + kb];
        #pragma unroll
        for (int i=0;i<4;i++)
            #pragma unroll
            for (int j=0;j<8;j++) e[i][j] += qv[i]*kv[j];
    }
    #pragma unroll
    for (int i=0;i<4;i++){
        int h = h0 + i;
        if ((h>>3) == tc) e[i][h&7] = NEG_INF;
    }
    #pragma unroll
    for (int i=0;i<4;i++){
        int h = h0 + i;
        float m = e[i][0];
        #pragma unroll
        for (int j=1;j<8;j++) m = fmaxf(m, e[i][j]);
        m = fmaxf(m, __shfl_xor(m,1));
        m = fmaxf(m, __shfl_xor(m,2));
        m = fmaxf(m, __shfl_xor(m,4));
        m = fmaxf(m, __shfl_xor(m,8));
        float s = 0.f;
        #pragma unroll
        for (int j=0;j<8;j++){ float pp = __expf(e[i][j]-m); e[i][j]=pp; s += pp; }
        s += __shfl_xor(s,1);
        s += __shfl_xor(s,2);
        s += __shfl_xor(s,4);
        s += __shfl_xor(s,8);
        if (tc == 0){
            mH[b*HW + h*128 + w] = m;
            sH[b*HW + h*128 + w] = s;
        }
        uint4 pw;
        pw.x = pk2(e[i][0], e[i][1]);
        pw.y = pk2(e[i][2], e[i][3]);
        pw.z = pk2(e[i][4], e[i][5]);
        pw.w = pk2(e[i][6], e[i][7]);
        *(uint4*)&p32[(h*64 + tc*4) ^ ((h&7)<<2)] = pw;
    }
    __syncthreads();

    int wv = t >> 6, l = t & 63;
    int lm = l & 15, lq = l >> 4;
    int mt = wv;
    f32x4 acc[4];
    #pragma unroll
    for (int nt=0; nt<4; nt++) acc[nt] = (f32x4){0.f,0.f,0.f,0.f};

    #pragma unroll
    for (int ks=0; ks<4; ks++){
        int ri = mt*16 + lm;
        s16x8 a = *(const s16x8*)&p32[(ri*64 + ks*16 + lq*4) ^ ((ri&7)<<2)];
        #pragma unroll
        for (int nt=0; nt<4; nt++){
            int c = nt*16 + lm;
            s16x8 bf_ = *(const s16x8*)&v32[(c*64 + ks*16 + lq*4) ^ ((c&7)<<2)];
            acc[nt] = __builtin_amdgcn_mfma_f32_16x16x32_bf16(a, bf_, acc[nt], 0, 0, 0);
        }
    }
    #pragma unroll
    for (int nt=0; nt<4; nt++){
        int c = nt*16 + lm;
        int hh = mt*16 + lq*4;
        uint2 st;
        st.x = pk2(acc[nt][0], acc[nt][1]);
        st.y = pk2(acc[nt][2], acc[nt][3]);
        *(uint2*)&colT[((size_t)(b*64+c)*128 + w)*128 + hh] = st;
    }
}

// ---------------------------------------------------------------- P3: row pass + combine (MFMA PV)
__global__ __launch_bounds__(512, 4) void k_row(
    const u16* __restrict__ qkv, const u16* __restrict__ colpart,
    const float* __restrict__ mH, const float* __restrict__ sH,
    const float* __restrict__ x, const float* __restrict__ y,
    const u16* __restrict__ xy,
    const float* __restrict__ gamma_p, float* __restrict__ out)
{
    __shared__ __align__(16) float q_s[8*128];
    __shared__ __align__(16) float k_sw[8*128];
    __shared__ __align__(16) u16  v_bf[64*128];
    __shared__ __align__(16) u16  p_bf[128*128];
    __shared__ float fc_s[128], fr_s[128];

    int t = threadIdx.x;
    int b = blockIdx.x >> 7, h = blockIdx.x & 127;
    const u32* src = (const u32*)(qkv + (size_t)b*NCH*HW + h*128);
    u32* v32 = (u32*)v_bf;
    u32* p32 = (u32*)p_bf;

    #pragma unroll
    for (int r=0;r<2;r++){
        int idx = t + r*512;
        int ch = idx >> 6, wp = idx & 63;
        u32 pk = src[ch*8192 + wp];
        int u0 = wp*2;
        if (ch < 8){
            *(float2*)&q_s[ch*128 + u0] = make_float2(b2f_lo(pk), b2f_hi(pk));
        } else {
            int o = ch - 8;
            k_sw[u0*8     + (o ^ ((u0>>3)&7))]     = b2f_lo(pk);
            k_sw[(u0+1)*8 + (o ^ (((u0+1)>>3)&7))] = b2f_hi(pk);
        }
    }
    #pragma unroll
    for (int r=0;r<8;r++){
        int idx = t + r*512;
        int c = idx >> 6, up = idx & 63;
        v32[(c*64 + up) ^ ((c&7)<<2)] = src[(16+c)*8192 + up];
    }
    __syncthreads();

    int tr = t >> 4, tc = t & 15;
    int w0 = tr*4, u0 = tc*8;
    float e[4][8];
    #pragma unroll
    for (int i=0;i<4;i++)
        #pragma unroll
        for (int j=0;j<8;j++) e[i][j] = 0.f;

    #pragma unroll
    for (int o=0;o<8;o++){
        float qv[4], kv[8];
        #pragma unroll
        for (int i=0;i<4;i++) qv[i] = q_s[o*128 + w0 + i];
        int kb = o ^ (tc & 7);
        #pragma unroll
        for (int j=0;j<8;j++) kv[j] = k_sw[(u0+j)*8 + kb];
        #pragma unroll
        for (int i=0;i<4;i++)
            #pragma unroll
            for (int j=0;j<8;j++) e[i][j] += qv[i]*kv[j];
    }
    int pixbase = b*HW + h*128;
    #pragma unroll
    for (int i=0;i<4;i++){
        int wp = w0 + i;
        float m = e[i][0];
        #pragma unroll
        for (int j=1;j<8;j++) m = fmaxf(m, e[i][j]);
        m = fmaxf(m, __shfl_xor(m,1));
        m = fmaxf(m, __shfl_xor(m,2));
        m = fmaxf(m, __shfl_xor(m,4));
        m = fmaxf(m, __shfl_xor(m,8));
        float mh = mH[pixbase + wp];
        float sh = sH[pixbase + wp];
        float mg = fmaxf(m, mh);
        float s = 0.f;
        #pragma unroll
        for (int j=0;j<8;j++){ float pp = __expf(e[i][j]-mg); e[i][j]=pp; s += pp; }
        s += __shfl_xor(s,1);
        s += __shfl_xor(s,2);
        s += __shfl_xor(s,4);
        s += __shfl_xor(s,8);
        if (tc == 0){
            float ef = __expf(mh - mg);
            float stot = sh*ef + s;
            fc_s[wp] = ef/stot;
            fr_s[wp] = 1.0f/stot;
        }
        uint4 pw;
        pw.x = pk2(e[i][0], e[i][1]);
        pw.y = pk2(e[i][2], e[i][3]);
        pw.z = pk2(e[i][4], e[i][5]);
        pw.w = pk2(e[i][6], e[i][7]);
        *(uint4*)&p32[(wp*64 + tc*4) ^ ((wp&7)<<2)] = pw;
    }
    __syncthreads();

    int wv = t >> 6, l = t & 63;
    int lm = l & 15, lq = l >> 4;
    int mt = wv;
    f32x4 acc[4];
    #pragma unroll
    for (int nt=0; nt<4; nt++) acc[nt] = (f32x4){0.f,0.f,0.f,0.f};

    #pragma unroll
    for (int ks=0; ks<4; ks++){
        int ri = mt*16 + lm;
        s16x8 a = *(const s16x8*)&p32[(ri*64 + ks*16 + lq*4) ^ ((ri&7)<<2)];
        #pragma unroll
        for (int nt=0; nt<4; nt++){
            int c = nt*16 + lm;
            s16x8 bf_ = *(const s16x8*)&v32[(c*64 + ks*16 + lq*4) ^ ((c&7)<<2)];
            acc[nt] = __builtin_amdgcn_mfma_f32_16x16x32_bf16(a, bf_, acc[nt], 0, 0, 0);
        }
    }
    float gm = gamma_p[0];
    int wq0 = mt*16 + lq*4;
    float fcv[4], frv[4];
    #pragma unroll
    for (int r2=0;r2<4;r2++){ fcv[r2] = fc_s[wq0+r2]; frv[r2] = fr_s[wq0+r2]; }

    #pragma unroll
    for (int nt=0; nt<4; nt++){
        int c = nt*16 + lm;
        size_t off = ((size_t)(b*64+c)*128 + h)*128 + wq0;
        uint2 cpv = *(const uint2*)&colpart[off];
        float cp[4] = {b2f_lo(cpv.x), b2f_hi(cpv.x), b2f_lo(cpv.y), b2f_hi(cpv.y)};
        float xs[4];
        if (xy){
            uint2 xv = *(const uint2*)&xy[off];
            xs[0]=b2f_lo(xv.x); xs[1]=b2f_hi(xv.x); xs[2]=b2f_lo(xv.y); xs[3]=b2f_hi(xv.y);
        } else {
            float4 x4 = *(const float4*)&x[off];
            float4 y4 = *(const float4*)&y[off];
            xs[0]=x4.x+y4.x; xs[1]=x4.y+y4.y; xs[2]=x4.z+y4.z; xs[3]=x4.w+y4.w;
        }
        float4 o4;
        o4.x = gm*(cp[0]*fcv[0] + acc[nt][0]*frv[0]) + xs[0];
        o4.y = gm*(cp[1]*fcv[1] + acc[nt][1]*frv[1]) + xs[1];
        o4.z = gm*(cp[2]*fcv[2] + acc[nt][2]*frv[2]) + xs[2];
        o4.w = gm*(cp[3]*fcv[3] + acc[nt][3]*frv[3]) + xs[3];
        *(float4*)&out[off] = o4;
    }
}

// ----------------------------------------------------------------
extern "C" void kernel_launch(void* const* d_in, const int* in_sizes, int n_in,
                              void* d_out, int out_size, void* d_ws, size_t ws_size,
                              hipStream_t stream)
{
    (void)in_sizes; (void)n_in; (void)out_size;
    const float* x  = (const float*)d_in[0];
    const float* y  = (const float*)d_in[1];
    const float* qw = (const float*)d_in[2];
    const float* qb = (const float*)d_in[3];
    const float* kw = (const float*)d_in[4];
    const float* kb = (const float*)d_in[5];
    const float* vw = (const float*)d_in[6];
    const float* vb = (const float*)d_in[7];
    const float* gm = (const float*)d_in[8];
    float* out = (float*)d_out;

    char* ws = (char*)d_ws;
    u16* qkv     = (u16*)(ws);                    // 41,943,040 B
    u16* qkvT    = (u16*)(ws + 41943040ull);      // 41,943,040 B
    u16* colT    = (u16*)(ws + 83886080ull);      // 33,554,432 B
    u16* colpart = qkvT;                          // alias: qkvT dead after k_col
    float* mH    = (float*)(ws + 117440512ull);   // 1,048,576 B
    float* sH    = (float*)(ws + 118489088ull);   // 1,048,576 B
    u16* wbf     = (u16*)(ws + 119537664ull);     // 20,480 B
    float* bias80= (float*)(ws + 119558144ull);   // 320 B
    u16* xybuf   = nullptr;                       // 33,554,432 B (optional)
    if (ws_size >= 119603200ull + 33554432ull)
        xybuf = (u16*)(ws + 119603200ull);

    k_wcvt<<<40, 256, 0, stream>>>(qw, qb, kw, kb, vw, vb, wbf, bias80);
    k_qkv_mfma<<<2048, 256, 0, stream>>>(x, y, wbf, bias80, qkv, xybuf);
    k_tr <<<5120, 256, 0, stream>>>(qkv, qkvT);          // 1280 planes
    k_col<<<2048, 512, 0, stream>>>(qkvT, colT, mH, sH);
    k_tr <<<4096, 256, 0, stream>>>(colT, colpart);      // 1024 planes
    k_row<<<2048, 512, 0, stream>>>(qkv, colpart, mH, sH, x, y, xybuf, gm, out);
}